// Round 7
// baseline (1029.659 us; speedup 1.0000x reference)
//
#include <hip/hip_runtime.h>

#define N_NODES 50000
#define E_EDGES 800000
#define D 256
#define L 128
#define CAP 64     // max in-degree bucket; Poisson(16) tail => P(overflow) ~ 1e-19
#define NC 16      // nodes per work chunk
#define NCHUNK ((N_NODES + NC - 1) / NC)   // 3125 chunks per slice
#define XCC_GETREG_ENC (20 | (7 << 11))    // HW_REG_XCC_ID, offset 0, size 8

typedef __attribute__((ext_vector_type(8))) short bf16x8;
typedef __attribute__((ext_vector_type(4))) float f32x4;

__device__ __forceinline__ float bf2f(unsigned short u) {
    union { unsigned int i; float f; } v; v.i = ((unsigned int)u) << 16; return v.f;
}
__device__ __forceinline__ unsigned short f2bf(float f) {  // round-to-nearest-even
    union { float f; unsigned int i; } v; v.f = f;
    unsigned int r = v.i + 0x7fffu + ((v.i >> 16) & 1u);
    return (unsigned short)(r >> 16);
}

__global__ __launch_bounds__(256) void zero_i(int* __restrict__ p, int n) {
    int i = blockIdx.x * 256 + threadIdx.x;
    if (i < n) p[i] = 0;
}

// Single-pass bucket build: cursor ends up = in-degree.
__global__ __launch_bounds__(256) void fill_fixed(const int* __restrict__ src,
                                                  const int* __restrict__ dst,
                                                  int* __restrict__ cursor,
                                                  int* __restrict__ bucket) {
    int e = blockIdx.x * 256 + threadIdx.x;
    if (e >= E_EDGES) return;
    int d = dst[e];
    int pos = atomicAdd(&cursor[d], 1);
    if (pos < CAP) bucket[d * CAP + pos] = src[e];
}

__global__ __launch_bounds__(256) void dinv_fin(const int* __restrict__ cursor,
                                                float* __restrict__ dinv) {
    int i = blockIdx.x * 256 + threadIdx.x;
    if (i < N_NODES) dinv[i] = rsqrtf((float)cursor[i] + 1.0f);
}

// Transpose + split weights into [n][k] bf16 hi/lo. Blocks 0..255: W1 (n=b, k=t).
// Blocks 256..511: Wcat = [Wmu | Wlv] (n=b-256, k=t). Block 256 also fills bcat.
__global__ __launch_bounds__(256) void prep_w(
    const float* __restrict__ W1, const float* __restrict__ Wmu,
    const float* __restrict__ Wlv, const float* __restrict__ bmu,
    const float* __restrict__ blv,
    unsigned short* __restrict__ W1h, unsigned short* __restrict__ W1l,
    unsigned short* __restrict__ Wch, unsigned short* __restrict__ Wcl,
    float* __restrict__ bcat) {
    int b = blockIdx.x, t = threadIdx.x;
    if (b < 256) {
        int n = b, k = t;
        float w = W1[k * 256 + n];
        unsigned short h = f2bf(w);
        W1h[n * 256 + k] = h;
        W1l[n * 256 + k] = f2bf(w - bf2f(h));
    } else {
        int n = b - 256, k = t;
        float w = (n < 128) ? Wmu[k * 128 + n] : Wlv[k * 128 + (n - 128)];
        unsigned short h = f2bf(w);
        Wch[n * 256 + k] = h;
        Wcl[n * 256 + k] = f2bf(w - bf2f(h));
        if (b == 256) bcat[t] = (t < 128) ? bmu[t] : blv[t - 128];
    }
}

// MFMA GEMM: C[M,256] = A_f32[M,256] @ (Bh+Bl)[256,256], fp32-split 3-term.
// Block = 64 rows x 256 cols, 4 waves x 16 rows -> grid 782 (3 blocks/CU).
__global__ __launch_bounds__(256, 3) void gemm_mfma(
    const float* __restrict__ A,
    const unsigned short* __restrict__ Bth, const unsigned short* __restrict__ Btl,
    unsigned short* __restrict__ Hout,
    float* __restrict__ mu, float* __restrict__ lv,
    const float* __restrict__ bias, int M, int mode)
{
    __shared__ unsigned short Bsh[256 * 32];
    __shared__ unsigned short Bsl[256 * 32];
    const int t = threadIdx.x;
    const int lane = t & 63, wave = t >> 6;
    const int row0 = blockIdx.x * 64 + wave * 16;
    const int m_ = lane & 15, q = lane >> 4;
    int rA = row0 + m_; if (rA >= M) rA = M - 1;
    const float* Ap = A + (size_t)rA * 256;
    const int bn = t >> 2;
    const int bc = t & 3;

    f32x4 acc[16];
    const f32x4 zf = {0.f, 0.f, 0.f, 0.f};
#pragma unroll
    for (int nt = 0; nt < 16; ++nt) acc[nt] = zf;

    for (int ks = 0; ks < 8; ++ks) {
        const int k0 = ks * 32;
        bf16x8 gbh[4], gbl[4];
#pragma unroll
        for (int i = 0; i < 4; ++i) {
            int n = bn + i * 64;
            gbh[i] = *(const bf16x8*)(Bth + n * 256 + k0 + bc * 8);
            gbl[i] = *(const bf16x8*)(Btl + n * 256 + k0 + bc * 8);
        }
        float4 av0 = *(const float4*)(Ap + k0 + q * 8);
        float4 av1 = *(const float4*)(Ap + k0 + q * 8 + 4);
        __syncthreads();
#pragma unroll
        for (int i = 0; i < 4; ++i) {
            int n = bn + i * 64;
            int cc = (bc ^ ((n >> 1) & 3)) * 8;
            *(bf16x8*)&Bsh[n * 32 + cc] = gbh[i];
            *(bf16x8*)&Bsl[n * 32 + cc] = gbl[i];
        }
        float af[8] = {av0.x, av0.y, av0.z, av0.w, av1.x, av1.y, av1.z, av1.w};
        bf16x8 ah, al;
#pragma unroll
        for (int j = 0; j < 8; ++j) {
            unsigned short h = f2bf(af[j]);
            ah[j] = (short)h;
            al[j] = (short)f2bf(af[j] - bf2f(h));
        }
        __syncthreads();
#pragma unroll
        for (int nt = 0; nt < 16; ++nt) {
            int n = nt * 16 + m_;
            int cr = (q ^ ((n >> 1) & 3)) * 8;
            bf16x8 bh = *(const bf16x8*)&Bsh[n * 32 + cr];
            bf16x8 bl = *(const bf16x8*)&Bsl[n * 32 + cr];
            acc[nt] = __builtin_amdgcn_mfma_f32_16x16x32_bf16(ah, bh, acc[nt], 0, 0, 0);
            acc[nt] = __builtin_amdgcn_mfma_f32_16x16x32_bf16(ah, bl, acc[nt], 0, 0, 0);
            acc[nt] = __builtin_amdgcn_mfma_f32_16x16x32_bf16(al, bh, acc[nt], 0, 0, 0);
        }
    }
    int rbase = row0 + q * 4;
#pragma unroll
    for (int r = 0; r < 4; ++r) {
        int grow = rbase + r;
        if (grow >= M) continue;
#pragma unroll
        for (int nt = 0; nt < 16; ++nt) {
            int gcol = nt * 16 + m_;
            float v = acc[nt][r];
            if (mode == 0) {
                Hout[(size_t)grow * 256 + gcol] = f2bf(v);
            } else {
                v += bias[gcol];
                if (gcol < 128) mu[(size_t)grow * 128 + gcol] = v;
                else            lv[(size_t)grow * 128 + (gcol - 128)] = v;
            }
        }
    }
}

// XCD-affine sliced gather. Slice s covers cols [s*32, s*32+32) = 64B/row;
// per-XCD working set = 3.2MB < 4MiB L2. Blocks read their REAL XCD id via
// s_getreg(HW_REG_XCC_ID) and drain that slice's chunk queue first, then steal
// (correct under any dispatch mapping). Wave layout: 8 edge-groups x 8 lanes,
// lane = ushort4 (8B) -> one 512B load instruction covers 8 edges.
// Edge (src,w) preloaded in lane registers, fetched per-group via ds_bpermute.
__global__ __launch_bounds__(256) void gather_xcd(
    const unsigned short* __restrict__ Hs,
    const int* __restrict__ bucket, const int* __restrict__ cnt_,
    const float* __restrict__ dinv, const float* __restrict__ bias,
    unsigned short* __restrict__ OutZ, float* __restrict__ OutY,
    int* __restrict__ qheads, int mode)
{
    __shared__ int chunk_s;
    const int xcd = __builtin_amdgcn_s_getreg(XCC_GETREG_ENC) & 7;
    const int t = threadIdx.x;
    const int wave = t >> 6, lane = t & 63;
    const int g = lane >> 3, li = lane & 7;      // edge-group, lane-in-group

    for (int qi = 0; qi < 8; ++qi) {
        const int q = (xcd + qi) & 7;            // slice / queue index
        const int c0 = q * 32;                   // column base of this slice
        while (true) {
            if (t == 0) chunk_s = atomicAdd(&qheads[q], 1);
            __syncthreads();
            const int chunk = chunk_s;
            __syncthreads();
            if (chunk >= NCHUNK) break;
            const int nbase = chunk * NC + wave;
#pragma unroll
            for (int nn = 0; nn < NC / 4; ++nn) {
                const int node = nbase + nn * 4;
                if (node >= N_NODES) break;
                int cnt = cnt_[node]; if (cnt > CAP) cnt = CAP;
                const float dn = dinv[node];
                // preload: lane j owns edge j's (src, weight)
                int s_l = 0; float w_l = 0.f;
                if (lane < cnt) {
                    s_l = bucket[node * CAP + lane];
                    w_l = dinv[s_l] * dn;
                }
                float a0 = 0.f, a1 = 0.f, a2 = 0.f, a3 = 0.f;
                if (g == 0) {  // self-loop (norm_ii = 1/deg)
                    float sl = dn * dn;
                    ushort4 h = *(const ushort4*)(Hs + (size_t)node * D + c0 + li * 4);
                    a0 = bf2f(h.x) * sl; a1 = bf2f(h.y) * sl;
                    a2 = bf2f(h.z) * sl; a3 = bf2f(h.w) * sl;
                }
                const int full = cnt & ~7;
                for (int j = 0; j < full; j += 8) {
                    int e = j + g;
                    int s = __builtin_amdgcn_ds_bpermute(e << 2, s_l);
                    float w = __int_as_float(
                        __builtin_amdgcn_ds_bpermute(e << 2, __float_as_int(w_l)));
                    ushort4 u = *(const ushort4*)(Hs + (size_t)s * D + c0 + li * 4);
                    a0 = fmaf(bf2f(u.x), w, a0); a1 = fmaf(bf2f(u.y), w, a1);
                    a2 = fmaf(bf2f(u.z), w, a2); a3 = fmaf(bf2f(u.w), w, a3);
                }
                {   // tail
                    int e = full + g;
                    int s = __builtin_amdgcn_ds_bpermute(e << 2, s_l);
                    float w = __int_as_float(
                        __builtin_amdgcn_ds_bpermute(e << 2, __float_as_int(w_l)));
                    if (e < cnt) {
                        ushort4 u = *(const ushort4*)(Hs + (size_t)s * D + c0 + li * 4);
                        a0 = fmaf(bf2f(u.x), w, a0); a1 = fmaf(bf2f(u.y), w, a1);
                        a2 = fmaf(bf2f(u.z), w, a2); a3 = fmaf(bf2f(u.w), w, a3);
                    }
                }
                // cross-group reduce (8 groups)
                a0 += __shfl_xor(a0, 8, 64); a0 += __shfl_xor(a0, 16, 64); a0 += __shfl_xor(a0, 32, 64);
                a1 += __shfl_xor(a1, 8, 64); a1 += __shfl_xor(a1, 16, 64); a1 += __shfl_xor(a1, 32, 64);
                a2 += __shfl_xor(a2, 8, 64); a2 += __shfl_xor(a2, 16, 64); a2 += __shfl_xor(a2, 32, 64);
                a3 += __shfl_xor(a3, 8, 64); a3 += __shfl_xor(a3, 16, 64); a3 += __shfl_xor(a3, 32, 64);
                if (g == 0) {
                    const int c = c0 + li * 4;
                    if (mode == 0) {
                        float4 b = *(const float4*)(bias + c);
                        a0 = fmaxf(a0 + b.x, 0.f); a1 = fmaxf(a1 + b.y, 0.f);
                        a2 = fmaxf(a2 + b.z, 0.f); a3 = fmaxf(a3 + b.w, 0.f);
                        ushort4 o; o.x = f2bf(a0); o.y = f2bf(a1); o.z = f2bf(a2); o.w = f2bf(a3);
                        *(ushort4*)(OutZ + (size_t)node * D + c) = o;
                    } else {
                        float4 o; o.x = a0; o.y = a1; o.z = a2; o.w = a3;
                        *(float4*)(OutY + (size_t)node * D + c) = o;
                    }
                }
            }
        }
    }
}

extern "C" void kernel_launch(void* const* d_in, const int* in_sizes, int n_in,
                              void* d_out, int out_size, void* d_ws, size_t ws_size,
                              hipStream_t stream) {
    const float* x   = (const float*)d_in[0];
    const int*   ei  = (const int*)d_in[1];
    const float* W1  = (const float*)d_in[2];
    const float* b1  = (const float*)d_in[3];
    const float* Wmu = (const float*)d_in[4];
    const float* bmu = (const float*)d_in[5];
    const float* Wlv = (const float*)d_in[6];
    const float* blv = (const float*)d_in[7];
    const int* src = ei;
    const int* dst = ei + E_EDGES;

    const size_t NF = (size_t)N_NODES * D;  // 12.8M
    unsigned short* Hb = (unsigned short*)d_ws;   // [N,256] bf16
    unsigned short* Z  = Hb + NF;                 // [N,256] bf16
    float* Y = (float*)(Z + NF);                  // [N,256] fp32
    unsigned short* W1h = (unsigned short*)(Y + NF);
    unsigned short* W1l = W1h + 65536;
    unsigned short* Wch = W1l + 65536;
    unsigned short* Wcl = Wch + 65536;
    float* bcat = (float*)(Wcl + 65536);
    float* dinv = bcat + 256;
    int* cursor = (int*)(dinv + N_NODES);   // [N]
    int* qh1    = cursor + N_NODES;         // [8]
    int* qh2    = qh1 + 8;                  // [8]
    int* bucket = qh2 + 8;                  // [N*CAP]
    float* mu = (float*)d_out;
    float* lv = mu + (size_t)N_NODES * L;

    // graph build: zero cursor + both queue heads together (adjacent)
    zero_i<<<(N_NODES + 16 + 255) / 256, 256, 0, stream>>>(cursor, N_NODES + 16);
    fill_fixed<<<(E_EDGES + 255) / 256, 256, 0, stream>>>(src, dst, cursor, bucket);
    dinv_fin<<<(N_NODES + 255) / 256, 256, 0, stream>>>(cursor, dinv);

    // weight prep
    prep_w<<<512, 256, 0, stream>>>(W1, Wmu, Wlv, bmu, blv, W1h, W1l, Wch, Wcl, bcat);

    const int gemm_blocks = (N_NODES + 63) / 64;   // 782
    // layer 1: H = X@W1 (bf16 out)
    gemm_mfma<<<gemm_blocks, 256, 0, stream>>>(x, W1h, W1l, Hb,
                                               nullptr, nullptr, nullptr, N_NODES, 0);
    // Z = relu(P·H + b1)
    gather_xcd<<<1024, 256, 0, stream>>>(Hb, bucket, cursor, dinv, b1,
                                         Z, nullptr, qh1, 0);
    // Y = P·Z (fp32)
    gather_xcd<<<1024, 256, 0, stream>>>(Z, bucket, cursor, dinv, nullptr,
                                         nullptr, Y, qh2, 1);
    // heads: [mu|lv] = Y@[Wmu|Wlv] + [bmu|blv]
    gemm_mfma<<<gemm_blocks, 256, 0, stream>>>(Y, Wch, Wcl, nullptr,
                                               mu, lv, bcat, N_NODES, 1);
}